// Round 1
// baseline (112.494 us; speedup 1.0000x reference)
//
#include <hip/hip_runtime.h>

__device__ __forceinline__ unsigned int part1by2(unsigned int n) {
    n &= 1023u;
    n = (n ^ (n << 16)) & 0xFF0000FFu;  // 4278190335
    n = (n ^ (n << 8))  & 0x0300F00Fu;  // 50393103
    n = (n ^ (n << 4))  & 0x030C30C3u;  // 51130563
    n = (n ^ (n << 2))  & 0x09249249u;  // 153391689
    return n;
}

// One thread per 16B quad of an output row: 8 threads per row, 64 threads
// (one wave) per parent voxel. q = quad id; r = q>>3 = output row;
// i = r>>3 = parent; j = r&7 = child index.
__global__ __launch_bounds__(256) void asv_kernel(
    const float* __restrict__ positions,
    const float* __restrict__ sizes,
    const float* __restrict__ densities,
    const float* __restrict__ colors,
    const int*   __restrict__ level_p,
    float* __restrict__ out,
    float* __restrict__ morton_out,
    int N)
{
    int q  = blockIdx.x * blockDim.x + threadIdx.x;
    int r  = q >> 3;
    int kq = q & 7;
    int i  = r >> 3;
    if (i >= N) return;
    int j  = r & 7;

    float4 v;
    if (kq == 0) {
        float s  = sizes[i];
        float t  = 0.25f * s;                 // exact (power-of-two scale)
        float px = positions[3 * i + 0];
        float py = positions[3 * i + 1];
        float pz = positions[3 * i + 2];
        // match jnp: round(off*size) then round(add); no FMA contraction
        float cx = __fadd_rn(px, (j & 1) ? t : -t);
        float cy = __fadd_rn(py, (j & 2) ? t : -t);
        float cz = __fadd_rn(pz, (j & 4) ? t : -t);

        int   gr  = 64 << level_p[0];
        float grf = (float)gr;
        // (c+1)/2*gr : add is rounded identically to ref; *0.5 and *gr exact
        int ix = (int)(__fmul_rn(__fmul_rn(__fadd_rn(cx, 1.0f), 0.5f), grf));
        int iy = (int)(__fmul_rn(__fmul_rn(__fadd_rn(cy, 1.0f), 0.5f), grf));
        int iz = (int)(__fmul_rn(__fmul_rn(__fadd_rn(cz, 1.0f), 0.5f), grf));
        ix = min(max(ix, 0), gr - 1);
        iy = min(max(iy, 0), gr - 1);
        iz = min(max(iz, 0), gr - 1);

        unsigned int code = (part1by2((unsigned)iz) << 2)
                          | (part1by2((unsigned)iy) << 1)
                          |  part1by2((unsigned)ix);
        morton_out[r] = (float)(int)code;     // harness reads whole buffer as f32

        v = make_float4(cx, cy, cz, 0.5f * s);
    } else if (kq == 1) {
        const float* c = colors + (size_t)i * 27;
        v = make_float4(densities[i], c[0], c[1], c[2]);
    } else {
        const float* c = colors + (size_t)i * 27 + (4 * kq - 5);
        v = make_float4(c[0], c[1], c[2], c[3]);
    }
    reinterpret_cast<float4*>(out)[q] = v;
}

extern "C" void kernel_launch(void* const* d_in, const int* in_sizes, int n_in,
                              void* d_out, int out_size, void* d_ws, size_t ws_size,
                              hipStream_t stream) {
    const float* positions = (const float*)d_in[0];
    const float* sizes     = (const float*)d_in[1];
    const float* densities = (const float*)d_in[2];
    const float* colors    = (const float*)d_in[3];
    const int*   level_p   = (const int*)d_in[4];

    int N = in_sizes[1];                      // sizes has N elements
    float* out        = (float*)d_out;
    float* morton_out = out + (size_t)N * 8 * 32;

    long long T = (long long)N * 64;          // 8 rows/parent * 8 quads/row
    int blocks  = (int)((T + 255) / 256);
    asv_kernel<<<blocks, 256, 0, stream>>>(positions, sizes, densities, colors,
                                           level_p, out, morton_out, N);
}